// Round 2
// baseline (2631.690 us; speedup 1.0000x reference)
//
#include <hip/hip_runtime.h>
#include <cstdint>
#include <cstddef>

#define DD 12
#define NNODE 32768
#define LTOK 3
#define KCH 4
#define HD 128
#define NC_STEP 896
#define KD_STEP 640
#define NC_EMB 128
#define KD_EMB 384

typedef unsigned short u16;
typedef __attribute__((ext_vector_type(8))) __bf16 bf16x8;
typedef __attribute__((ext_vector_type(4))) float f32x4;

__device__ __forceinline__ float bf2f(unsigned int u) {
  union { unsigned int i; float f; } v; v.i = (u & 0xffffu) << 16; return v.f;
}
__device__ __forceinline__ u16 f2bf(float f) {
  union { float f; unsigned int i; } v; v.f = f;
  unsigned int x = v.i;
  return (u16)((x + 0x7fffu + ((x >> 16) & 1u)) >> 16);
}
__device__ __forceinline__ float sigm(float x) { return 1.f / (1.f + __expf(-x)); }
__device__ __forceinline__ float tanh_fast(float x) { return 1.f - 2.f / (1.f + __expf(2.f * x)); }
__device__ __forceinline__ void async16(const void* g, void* l) {
  __builtin_amdgcn_global_load_lds((const __attribute__((address_space(1))) unsigned int*)g,
                                   (__attribute__((address_space(3))) unsigned int*)l, 16, 0, 0);
}

// ---------------------------------------------------------------------------
// R11 step GEMM: pre[32768,896] = A[32768,640] @ Ubig[896,640]^T + bias.
// A columns: k<512 -> h_prev[children] gather (bf16), k>=512 -> tbf (bf16
// shadow of tslice, same f2bf rounding as the old f32 path).
// 8-phase deep-pipelined schedule (T3+T4+T5 on top of existing T2 swizzle):
//   BM=256 x BN=128, BK=64, 512 thr / 8 waves, per-wave 128x32 output.
//   Per K-tile: 4 phases {ds_read af[p],af[p+4] (+all bf at p0) | issue 2
//   global_load_lds for tile t+1 | s_barrier | lgkmcnt(0) | setprio(1)
//   8 MFMA setprio(0) | counted vmcnt | s_barrier}.
// vmcnt ledger (per-wave FIFO: B0,B1 @p0; A0,A1 @p1; A2,A3 @p2):
//   p3-end: vmcnt(2) drains B,B,A0,A1 of tile t+1, leaves A2,A3 in flight.
//   p0-end: vmcnt(2) drains A2,A3 (leaves newly issued B',B').
//   Phase p reads A-rows staged by producers' jj{0,1} (p even-slab pairs
//   mt=p and mt=p+4), so the counted waits are exactly sufficient; every
//   drain precedes a barrier that precedes the consuming ds_read.
// Raw s_barrier throughout (no compiler vmcnt(0) drain). Loads never
// drain-to-0 in the main loop (T4).
// LDS rows UNPADDED 128 B (global_load_lds lands base+L*16); XOR swizzle:
// physical 16B chunk s of row r holds global chunk s^(r&7) -> conflict-free.
// Grid: 1-D 896 blocks, bijective chunked XCD swizzle (896 = 8*112),
// col-tile fastest within an XCD chunk -> 7 blocks sharing one gathered
// A-panel run concurrently on one XCD's L2 (cuts A re-fetch from HBM).
// ---------------------------------------------------------------------------
#define BM 256
#define BN 128
#define BK 64

__global__ __launch_bounds__(512) void gemm8_k(
    const u16* __restrict__ Abf, const u16* __restrict__ Tbf,
    const int* __restrict__ gidx, const u16* __restrict__ B,
    const float* __restrict__ bias, u16* __restrict__ outb,
    const u16* __restrict__ zbuf)
{
  __shared__ u16 As[2][BM * BK];   // 2 x 32 KB
  __shared__ u16 Bs[2][BN * BK];   // 2 x 16 KB
  const int t = threadIdx.x;
  const int w = t >> 6;            // 0..7
  const int L = t & 63;
  const int q = L >> 4;
  const int lrow8 = L >> 3;        // row within 8-row slab
  const int sub = L & 7;           // 16B landing slot
  const int swz = sub ^ lrow8;     // global chunk this lane fetches

  // bijective chunked XCD swizzle: 896 = 8 * 112
  const int bid = blockIdx.x;
  const int wg = (bid & 7) * 112 + (bid >> 3);
  const int rt = wg / 7;
  const int ct = wg - rt * 7;
  const int row0 = rt * BM;
  const int col0 = ct * BN;

  const int wm = w >> 2;           // 0..1 : 128-row group
  const int wn = w & 3;            // 0..3 : 32-col group
  const int mrow = wm * 128;
  const int ncol = wn * 32;

  f32x4 acc[8][2];
#pragma unroll
  for (int a = 0; a < 8; ++a)
#pragma unroll
    for (int b = 0; b < 2; ++b)
      acc[a][b] = f32x4{0.f, 0.f, 0.f, 0.f};

  // gather indices for this wave's 4 A-slabs (global rows row0 + w*32 + jj*8 + lrow8)
  int4 cidx[4];
#pragma unroll
  for (int jj = 0; jj < 4; ++jj)
    cidx[jj] = *(const int4*)&gidx[(row0 + w * 32 + jj * 8 + lrow8) * KCH];

  auto stageB = [&](const int k0, const int sel, const int jb) {
    const int r = w * 16 + jb * 8;
    async16(B + (size_t)(col0 + r + lrow8) * KD_STEP + k0 + swz * 8,
            &Bs[sel][r * BK]);
  };
  auto stageA = [&](const int k0, const int sel, const int jj) {
    const int rbase = w * 32 + jj * 8;
    const u16* src;
    if (k0 < 4 * HD) {
      const int id = ((const int*)&cidx[jj])[k0 >> 7];
      const u16* base = (id >= 1) ? (Abf + (size_t)(id - 1) * HD) : zbuf;
      src = base + (k0 & 127) + swz * 8;
    } else {
      src = Tbf + (size_t)(row0 + rbase + lrow8) * HD + (k0 - 4 * HD) + swz * 8;
    }
    async16(src, &As[sel][rbase * BK]);
  };

  // prologue: stage tile 0 fully, full drain, barrier
  stageB(0, 0, 0); stageB(0, 0, 1);
  stageA(0, 0, 0); stageA(0, 0, 1); stageA(0, 0, 2); stageA(0, 0, 3);
  asm volatile("s_waitcnt vmcnt(0)" ::: "memory");
  __builtin_amdgcn_s_barrier();

  constexpr int NT = KD_STEP / BK;   // 10
  bf16x8 bf[2][2];                   // [nt][ks], live across phases of a tile
#pragma unroll
  for (int tt = 0; tt < NT; ++tt) {
    const int rd = tt & 1, wr = (tt + 1) & 1;
    const int k1 = (tt + 1) * BK;
#pragma unroll
    for (int p = 0; p < 4; ++p) {
      // --- ds-read register subtile for this phase ---
      if (p == 0) {
#pragma unroll
        for (int nt = 0; nt < 2; ++nt)
#pragma unroll
          for (int ks = 0; ks < 2; ++ks)
            bf[nt][ks] = *(const bf16x8*)&Bs[rd][(ncol + nt * 16 + (L & 15)) * BK +
                                                 (((ks * 4 + q) ^ (L & 7)) * 8)];
      }
      bf16x8 af[2][2];   // [half (mt=p / mt=p+4)][ks]
#pragma unroll
      for (int half = 0; half < 2; ++half)
#pragma unroll
        for (int ks = 0; ks < 2; ++ks)
          af[half][ks] = *(const bf16x8*)&As[rd][(mrow + (p + half * 4) * 16 + (L & 15)) * BK +
                                                 (((ks * 4 + q) ^ (L & 7)) * 8)];
      // --- issue this phase's share of next-tile staging ---
      if (tt + 1 < NT) {
        if (p == 0)      { stageB(k1, wr, 0); stageB(k1, wr, 1); }
        else if (p == 1) { stageA(k1, wr, 0); stageA(k1, wr, 1); }
        else if (p == 2) { stageA(k1, wr, 2); stageA(k1, wr, 3); }
      }
      __builtin_amdgcn_s_barrier();
      asm volatile("s_waitcnt lgkmcnt(0)" ::: "memory");
      __builtin_amdgcn_sched_barrier(0);
      __builtin_amdgcn_s_setprio(1);
#pragma unroll
      for (int half = 0; half < 2; ++half)
#pragma unroll
        for (int nt = 0; nt < 2; ++nt)
#pragma unroll
          for (int ks = 0; ks < 2; ++ks)
            acc[p + half * 4][nt] = __builtin_amdgcn_mfma_f32_16x16x32_bf16(
                af[half][ks], bf[nt][ks], acc[p + half * 4][nt], 0, 0, 0);
      __builtin_amdgcn_s_setprio(0);
      __builtin_amdgcn_sched_barrier(0);
      // --- counted vmcnt ledger ---
      if (p == 0) {
        if (tt + 1 < NT) asm volatile("s_waitcnt vmcnt(2)" ::: "memory");
        else             asm volatile("s_waitcnt vmcnt(0)" ::: "memory");
      }
      if (p == 3 && tt + 1 < NT) asm volatile("s_waitcnt vmcnt(2)" ::: "memory");
      __builtin_amdgcn_s_barrier();
    }
  }

  // epilogue: C/D layout col=lane&15, row=(lane>>4)*4+i
#pragma unroll
  for (int nt = 0; nt < 2; ++nt) {
    const int col = col0 + ncol + nt * 16 + (L & 15);
    const float bb = bias[col];
#pragma unroll
    for (int mt = 0; mt < 8; ++mt) {
#pragma unroll
      for (int i = 0; i < 4; ++i) {
        const int row = row0 + mrow + mt * 16 + q * 4 + i;
        outb[(size_t)row * NC_STEP + col] = f2bf(acc[mt][nt][i] + bb);
      }
    }
  }
}

// ---------------------------------------------------------------------------
// Embed GEMM (R0-proven single-buffer structure):
// tslice[f32] & tbf[bf16] = gather(Ebf, tokens) @ Lbf^T + lin_b
// ---------------------------------------------------------------------------
__global__ __launch_bounds__(256) void gemm_emb_k(
    const u16* __restrict__ Ebf, const int* __restrict__ tokd,
    const u16* __restrict__ Lbf, const float* __restrict__ bias,
    float* __restrict__ outf, u16* __restrict__ outb)
{
  __shared__ u16 As[128 * 64];
  __shared__ u16 Bs[128 * 64];
  const int t = threadIdx.x;
  const int w = t >> 6;
  const int L = t & 63;
  const int q = L >> 4;
  const int lrow8 = L >> 3;
  const int sub = L & 7;
  const int swz = sub ^ lrow8;
  const int row0 = blockIdx.x * 128;

  f32x4 acc[4][4];
#pragma unroll
  for (int a = 0; a < 4; ++a)
#pragma unroll
    for (int b = 0; b < 4; ++b)
      acc[a][b] = f32x4{0.f, 0.f, 0.f, 0.f};

  const int mrow = (w & 1) * 64;
  const int ncol = (w >> 1) * 64;

  int4 cidx[4];
#pragma unroll
  for (int jj = 0; jj < 4; ++jj) {
    const int rit = w * 32 + jj * 8 + lrow8;
    cidx[jj].x = tokd[(row0 + rit) * LTOK + 0];
    cidx[jj].y = tokd[(row0 + rit) * LTOK + 1];
    cidx[jj].z = tokd[(row0 + rit) * LTOK + 2];
    cidx[jj].w = 0;
  }

#pragma unroll
  for (int k0 = 0; k0 < KD_EMB; k0 += 64) {
    __syncthreads();
#pragma unroll
    for (int jj = 0; jj < 4; ++jj) {
      const int id = ((const int*)&cidx[jj])[k0 >> 7];
      const u16* base = Ebf + (size_t)id * HD;
      const int rit = w * 32 + jj * 8 + lrow8;
      async16(base + (k0 & 127) + swz * 8, &As[(w * 32 + jj * 8) * 64]);
      async16(Lbf + (size_t)rit * KD_EMB + k0 + swz * 8, &Bs[(w * 32 + jj * 8) * 64]);
    }
    __syncthreads();
#pragma unroll
    for (int ks = 0; ks < 2; ++ks) {
      bf16x8 af[4], bfr[4];
      const int pc = ((ks * 4 + q) ^ (L & 7)) * 8;
#pragma unroll
      for (int mt = 0; mt < 4; ++mt)
        af[mt] = *(const bf16x8*)&As[(mrow + mt * 16 + (L & 15)) * 64 + pc];
#pragma unroll
      for (int nt = 0; nt < 4; ++nt)
        bfr[nt] = *(const bf16x8*)&Bs[(ncol + nt * 16 + (L & 15)) * 64 + pc];
#pragma unroll
      for (int mt = 0; mt < 4; ++mt)
#pragma unroll
        for (int nt = 0; nt < 4; ++nt)
          acc[mt][nt] = __builtin_amdgcn_mfma_f32_16x16x32_bf16(af[mt], bfr[nt], acc[mt][nt], 0, 0, 0);
    }
  }

#pragma unroll
  for (int nt = 0; nt < 4; ++nt) {
    const int col = ncol + nt * 16 + (L & 15);
    const float bb = bias[col];
#pragma unroll
    for (int mt = 0; mt < 4; ++mt) {
#pragma unroll
      for (int i = 0; i < 4; ++i) {
        const int row = row0 + mrow + mt * 16 + q * 4 + i;
        const float v = acc[mt][nt][i] + bb;
        outf[(size_t)row * NC_EMB + col] = v;
        outb[(size_t)row * NC_EMB + col] = f2bf(v);
      }
    }
  }
}

// ---------------------------------------------------------------------------
// LSTM cell: f = sum_k sig(pre_fk)*c_k ; gates ; c (f32), h (bf16),
// t += h (f32) and bf16 shadow tbf.
// ---------------------------------------------------------------------------
__global__ __launch_bounds__(256) void cell_k(
    const u16* __restrict__ pre, const int* __restrict__ idxs,
    const float* __restrict__ c_prev, float* __restrict__ c_cur,
    u16* __restrict__ h_cur, float* __restrict__ t_io, u16* __restrict__ tbf)
{
  const int g = blockIdx.x * 256 + threadIdx.x;
  const int r = g >> 7;
  const int j = g & 127;
  const u16* pr = pre + (size_t)r * NC_STEP;
  float f = 0.f;
#pragma unroll
  for (int k = 0; k < KCH; ++k) {
    const int id = idxs[r * KCH + k];
    const float cg = (id >= 1) ? c_prev[(size_t)(id - 1) * HD + j] : 0.f;
    f += sigm(bf2f(pr[k * HD + j])) * cg;
  }
  const float iv = sigm(bf2f(pr[4 * HD + j]));
  const float uv = tanh_fast(bf2f(pr[5 * HD + j]));
  const float ov = sigm(bf2f(pr[6 * HD + j]));
  const float cn = iv * uv + f;
  const float hv = ov * tanh_fast(cn);
  c_cur[g] = cn;
  h_cur[g] = f2bf(hv);
  const float tn = t_io[g] + hv;
  t_io[g] = tn;
  tbf[g] = f2bf(tn);
}

__global__ __launch_bounds__(256) void conv_k(const float* __restrict__ src,
                                              u16* __restrict__ dst, int n4)
{
  const int g = blockIdx.x * 256 + threadIdx.x;
  if (g < n4) {
    float4 v = ((const float4*)src)[g];
    ((ushort4*)dst)[g] = make_ushort4(f2bf(v.x), f2bf(v.y), f2bf(v.z), f2bf(v.w));
  }
}

// Build U_big[l][896][640] (bf16) = [Uf;Uiuo | W_w(mapped)] + fused f32 biases.
__global__ __launch_bounds__(256) void prep_k(
    const float* __restrict__ Uf_w, const float* __restrict__ Uf_b,
    const float* __restrict__ Uiuo_w, const float* __restrict__ Uiuo_b,
    const float* __restrict__ W_w, const float* __restrict__ W_b,
    u16* __restrict__ Ubig, float* __restrict__ biasbig)
{
  const int l = blockIdx.y;
  const int e = blockIdx.x * 256 + threadIdx.x;
  const int c = e / KD_STEP;
  const int k = e % KD_STEP;
  float v;
  if (k < 512) {
    v = (c < 512) ? Uf_w[((size_t)l * 512 + c) * 512 + k]
                  : Uiuo_w[((size_t)l * 384 + (c - 512)) * 512 + k];
  } else {
    const int q = k - 512;
    const int wr = (c < 512) ? (c & 127) : (128 + (c - 512));
    v = W_w[((size_t)l * 512 + wr) * 128 + q];
  }
  Ubig[((size_t)l * 896 + c) * 640 + k] = f2bf(v);
  if (e < 896) {
    const float b = (e < 512)
        ? (Uf_b[l * 512 + e] + W_b[l * 512 + (e & 127)])
        : (Uiuo_b[l * 384 + (e - 512)] + W_b[l * 512 + 128 + (e - 512)]);
    biasbig[l * 896 + e] = b;
  }
}

// Output (FLOAT32): hx = tile(t_final,2), cx = tile(c_final,2).
__global__ __launch_bounds__(256) void fin_k(
    const float* __restrict__ t_fin, const float* __restrict__ c_fin,
    float* __restrict__ out)
{
  const size_t NH = (size_t)NNODE * HD;
  const size_t g = (size_t)blockIdx.x * 256 + threadIdx.x;
  const float h = t_fin[g];
  const float c = c_fin[g];
  out[g] = h;
  out[NH + g] = h;
  out[2 * NH + g] = c;
  out[3 * NH + g] = c;
}

extern "C" void kernel_launch(void* const* d_in, const int* in_sizes, int n_in,
                              void* d_out, int out_size, void* d_ws, size_t ws_size,
                              hipStream_t stream)
{
  (void)in_sizes; (void)n_in; (void)out_size; (void)ws_size;
  const int*   tokens  = (const int*)d_in[0];
  const int*   indices = (const int*)d_in[1];
  const float* E       = (const float*)d_in[2];
  const float* lin_w   = (const float*)d_in[3];
  const float* lin_b   = (const float*)d_in[4];
  const float* Uf_w    = (const float*)d_in[5];
  const float* Uf_b    = (const float*)d_in[6];
  const float* Uiuo_w  = (const float*)d_in[7];
  const float* Uiuo_b  = (const float*)d_in[8];
  const float* W_w     = (const float*)d_in[9];
  const float* W_b     = (const float*)d_in[10];
  float* out = (float*)d_out;   // FLOAT32 output (R8-proven)

  const size_t NH = (size_t)NNODE * HD;

  char* ws = (char*)d_ws;
  size_t off = 0;
  auto alloc = [&](size_t bytes) -> void* {
    void* p = ws + off;
    off = (off + bytes + 255) & ~(size_t)255;
    return p;
  };
  u16*   Ubig    = (u16*)alloc((size_t)2 * 896 * 640 * 2);
  float* biasbig = (float*)alloc(2 * 896 * 4);
  u16*   Ebf     = (u16*)alloc((size_t)50000 * HD * 2);
  u16*   Lbf     = (u16*)alloc((size_t)HD * KD_EMB * 2);
  float* tslice  = (float*)alloc(NH * 4);
  u16*   tbf     = (u16*)alloc(NH * 2);
  u16*   h0a     = (u16*)alloc(NH * 2);
  u16*   h0b     = (u16*)alloc(NH * 2);
  u16*   h1a     = (u16*)alloc(NH * 2);
  u16*   h1b     = (u16*)alloc(NH * 2);
  float* c0a     = (float*)alloc(NH * 4);
  float* c0b     = (float*)alloc(NH * 4);
  float* c1a     = (float*)alloc(NH * 4);
  float* c1b     = (float*)alloc(NH * 4);
  u16*   pre     = (u16*)alloc((size_t)NNODE * NC_STEP * 2);
  u16*   zbuf    = (u16*)alloc(512);

  u16*   h0[2] = {h0a, h0b};
  u16*   h1[2] = {h1a, h1b};
  float* c0[2] = {c0a, c0b};
  float* c1[2] = {c1a, c1b};

  hipMemsetAsync(zbuf, 0, 512, stream);
  hipMemsetAsync(h0[0], 0, NH * 2, stream);
  hipMemsetAsync(h1[0], 0, NH * 2, stream);
  hipMemsetAsync(c0[0], 0, NH * 4, stream);
  hipMemsetAsync(c1[0], 0, NH * 4, stream);
  prep_k<<<dim3(2240, 2), 256, 0, stream>>>(Uf_w, Uf_b, Uiuo_w, Uiuo_b, W_w, W_b,
                                            Ubig, biasbig);
  conv_k<<<dim3((50000 * HD / 4 + 255) / 256), 256, 0, stream>>>(E, Ebf, 50000 * HD / 4);
  conv_k<<<dim3((HD * KD_EMB / 4 + 255) / 256), 256, 0, stream>>>(lin_w, Lbf, HD * KD_EMB / 4);

  for (int d = 0; d < DD; ++d) {
    const int ri = d & 1, wi = (d + 1) & 1;
    const int* idxd = indices + (size_t)d * NNODE * KCH;
    const int* tokd = tokens + (size_t)d * NNODE * LTOK;

    // tslice (f32) + tbf (bf16) = gather(Ebf, tokens[d]) @ Lbf^T + lin_b
    gemm_emb_k<<<dim3(NNODE / 128), 256, 0, stream>>>(
        Ebf, tokd, Lbf, lin_b, tslice, tbf);

    for (int l = 0; l < 2; ++l) {
      const u16*   hp = (l == 0) ? h0[ri] : h1[ri];
      u16*         hc = (l == 0) ? h0[wi] : h1[wi];
      const float* cp = (l == 0) ? c0[ri] : c1[ri];
      float*       cc = (l == 0) ? c0[wi] : c1[wi];
      const u16* Ul = Ubig + (size_t)l * 896 * 640;
      const float* bl = biasbig + l * 896;
      gemm8_k<<<dim3((NNODE / BM) * (NC_STEP / BN)), 512, 0, stream>>>(
          hp, tbf, idxd, Ul, bl, pre, zbuf);
      cell_k<<<dim3((int)(NH / 256)), 256, 0, stream>>>(
          pre, idxd, cp, cc, hc, tslice, tbf);
    }
  }
  // after d=11: tslice = t_final, c1[0] = c_final
  fin_k<<<dim3((int)(NH / 256)), 256, 0, stream>>>(tslice, c1[0], out);
}

// Round 3
// 2326.675 us; speedup vs baseline: 1.1311x; 1.1311x over previous
//
#include <hip/hip_runtime.h>
#include <cstdint>
#include <cstddef>

#define DD 12
#define NNODE 32768
#define LTOK 3
#define KCH 4
#define HD 128
#define NC_STEP 896
#define KD_STEP 640
#define NC_EMB 128
#define KD_EMB 384

typedef unsigned short u16;
typedef __attribute__((ext_vector_type(8))) __bf16 bf16x8;
typedef __attribute__((ext_vector_type(4))) float f32x4;

__device__ __forceinline__ float bf2f(unsigned int u) {
  union { unsigned int i; float f; } v; v.i = (u & 0xffffu) << 16; return v.f;
}
__device__ __forceinline__ u16 f2bf(float f) {
  union { float f; unsigned int i; } v; v.f = f;
  unsigned int x = v.i;
  return (u16)((x + 0x7fffu + ((x >> 16) & 1u)) >> 16);
}
__device__ __forceinline__ float sigm(float x) { return 1.f / (1.f + __expf(-x)); }
__device__ __forceinline__ float tanh_fast(float x) { return 1.f - 2.f / (1.f + __expf(2.f * x)); }
__device__ __forceinline__ void async16(const void* g, void* l) {
  __builtin_amdgcn_global_load_lds((const __attribute__((address_space(1))) unsigned int*)g,
                                   (__attribute__((address_space(3))) unsigned int*)l, 16, 0, 0);
}

// ---------------------------------------------------------------------------
// R12 step GEMM: pre[32768,896] = A[32768,640] @ Ubig[896,640]^T + bias.
// A cols: k<512 -> h_prev[children] gather (bf16), k>=512 -> tbf shadow.
// BM=256 x BN=128, BK=64, 512 thr / 8 waves (4M x 2N -> per-wave 64x64 out).
// 3-buffer LDS (144 KB), ONE raw s_barrier per K-tile (R2 post-mortem: 8
// barriers/tile with 8 MFMA between them was pure sync overhead).
// Schedule per tile t (buf rd = t%3):
//   issue 6 global_load_lds for tile t+2 -> buf[(t+2)%3]   (issue-early)
//   ds_read 16x b128 fragments from buf[rd]
//   setprio(1) 32x MFMA setprio(0)
//   vmcnt(6)  -- drains S(t+1) (issued one full tile ago; FIFO leaves the
//                6 just-issued S(t+2) in flight: never drain-to-0 mid-loop)
//   s_barrier -- after it, every wave's S(t+1) has landed -> t+1 reads safe
// Race-freedom:
//   RAW: S(t+1) issued in tile t-1; end-of-tile-t vmcnt(6) leaves only
//        S(t+2) outstanding => S(t+1) complete in ALL waves before the
//        barrier that precedes tile t+1's ds_reads.
//   WAR: S(t+2) writes buf[(t+2)%3] = buf[(t-1)%3]; its readers (tile t-1)
//        finished before barrier t-1, which precedes these issues.
// LDS rows UNPADDED 128 B (global_load_lds lands base+lane*16); XOR swizzle:
// physical 16B slot s of row r holds global chunk s^(r&7); fragment read at
// slot ((ks*4+q)^(L&7)) -> conflict-free (verified 0 in R0/R1/R2).
// Grid: 1-D 896, bijective chunked XCD swizzle (896=8*112), col-tile fastest
// within chunk -> 7 blocks sharing one gathered A-panel co-run on one XCD's
// L2 (R2-proven: FETCH 88.8 -> 37.1 MB).
// ---------------------------------------------------------------------------
#define BM 256
#define BN 128
#define BK 64

__global__ __launch_bounds__(512, 2) void gemm8_k(
    const u16* __restrict__ Abf, const u16* __restrict__ Tbf,
    const int* __restrict__ gidx, const u16* __restrict__ B,
    const float* __restrict__ bias, u16* __restrict__ outb,
    const u16* __restrict__ zbuf)
{
  __shared__ u16 As[3][BM * BK];   // 3 x 32 KB
  __shared__ u16 Bs[3][BN * BK];   // 3 x 16 KB
  const int t = threadIdx.x;
  const int w = t >> 6;            // 0..7
  const int L = t & 63;
  const int q = L >> 4;
  const int lrow8 = L >> 3;        // row within 8-row slab
  const int sub = L & 7;           // 16B landing slot
  const int swz = sub ^ lrow8;     // global chunk this lane fetches

  // bijective chunked XCD swizzle: 896 = 8 * 112
  const int bid = blockIdx.x;
  const int wg = (bid & 7) * 112 + (bid >> 3);
  const int rt = wg / 7;
  const int ct = wg - rt * 7;
  const int row0 = rt * BM;
  const int col0 = ct * BN;

  const int wm = w >> 1;           // 0..3 : 64-row group
  const int wn = w & 1;            // 0..1 : 64-col group
  const int mrow = wm * 64;
  const int ncol = wn * 64;

  f32x4 acc[4][4];
#pragma unroll
  for (int a = 0; a < 4; ++a)
#pragma unroll
    for (int b = 0; b < 4; ++b)
      acc[a][b] = f32x4{0.f, 0.f, 0.f, 0.f};

  // gather indices for this wave's 4 A-slabs (rows row0 + w*32 + jj*8 + lrow8)
  int4 cidx[4];
#pragma unroll
  for (int jj = 0; jj < 4; ++jj)
    cidx[jj] = *(const int4*)&gidx[(row0 + w * 32 + jj * 8 + lrow8) * KCH];

  // stage all 6 slabs (2 B + 4 A) of k-chunk [k0,k0+64) into buffer sel.
  // k0 must be compile-time (static cidx indexing).
  auto stageAll = [&](const int k0, const int sel) {
#pragma unroll
    for (int jb = 0; jb < 2; ++jb) {
      const int r = w * 16 + jb * 8;
      async16(B + (size_t)(col0 + r + lrow8) * KD_STEP + k0 + swz * 8,
              &Bs[sel][r * BK]);
    }
#pragma unroll
    for (int jj = 0; jj < 4; ++jj) {
      const int rbase = w * 32 + jj * 8;
      const u16* src;
      if (k0 < 4 * HD) {
        const int id = ((const int*)&cidx[jj])[k0 >> 7];
        const u16* base = (id >= 1) ? (Abf + (size_t)(id - 1) * HD) : zbuf;
        src = base + (k0 & 127) + swz * 8;
      } else {
        src = Tbf + (size_t)(row0 + rbase + lrow8) * HD + (k0 - 4 * HD) + swz * 8;
      }
      async16(src, &As[sel][rbase * BK]);
    }
  };

  // prologue: stage tiles 0 and 1; wait for tile 0 (leave tile 1 in flight)
  stageAll(0, 0);
  stageAll(64, 1);
  asm volatile("s_waitcnt vmcnt(6)" ::: "memory");
  __builtin_amdgcn_sched_barrier(0);
  __builtin_amdgcn_s_barrier();
  __builtin_amdgcn_sched_barrier(0);

  constexpr int NT = KD_STEP / BK;   // 10
#pragma unroll
  for (int tt = 0; tt < NT; ++tt) {
    const int rd = tt % 3;
    // issue-early: next-next tile staging (buffer's readers done at barrier tt-1)
    if (tt + 2 < NT) stageAll((tt + 2) * BK, (tt + 2) % 3);

    // fragment reads (compiler inserts lgkmcnt before MFMA use)
    bf16x8 af[4][2], bfv[4][2];
#pragma unroll
    for (int mt = 0; mt < 4; ++mt)
#pragma unroll
      for (int ks = 0; ks < 2; ++ks)
        af[mt][ks] = *(const bf16x8*)&As[rd][(mrow + mt * 16 + (L & 15)) * BK +
                                            (((ks * 4 + q) ^ (L & 7)) * 8)];
#pragma unroll
    for (int nt = 0; nt < 4; ++nt)
#pragma unroll
      for (int ks = 0; ks < 2; ++ks)
        bfv[nt][ks] = *(const bf16x8*)&Bs[rd][(ncol + nt * 16 + (L & 15)) * BK +
                                             (((ks * 4 + q) ^ (L & 7)) * 8)];

    __builtin_amdgcn_s_setprio(1);
#pragma unroll
    for (int ks = 0; ks < 2; ++ks)
#pragma unroll
      for (int mt = 0; mt < 4; ++mt)
#pragma unroll
        for (int nt = 0; nt < 4; ++nt)
          acc[mt][nt] = __builtin_amdgcn_mfma_f32_16x16x32_bf16(
              af[mt][ks], bfv[nt][ks], acc[mt][nt], 0, 0, 0);
    __builtin_amdgcn_s_setprio(0);

    // tile-end sync: counted vmcnt + ONE barrier
    if (tt < NT - 1) {
      if (tt + 2 < NT) asm volatile("s_waitcnt vmcnt(6)" ::: "memory");
      else             asm volatile("s_waitcnt vmcnt(0)" ::: "memory");
      __builtin_amdgcn_sched_barrier(0);
      __builtin_amdgcn_s_barrier();
      __builtin_amdgcn_sched_barrier(0);
    }
  }

  // epilogue: C/D layout col=lane&15, row=(lane>>4)*4+i
#pragma unroll
  for (int nt = 0; nt < 4; ++nt) {
    const int col = col0 + ncol + nt * 16 + (L & 15);
    const float bb = bias[col];
#pragma unroll
    for (int mt = 0; mt < 4; ++mt) {
#pragma unroll
      for (int i = 0; i < 4; ++i) {
        const int row = row0 + mrow + mt * 16 + q * 4 + i;
        outb[(size_t)row * NC_STEP + col] = f2bf(acc[mt][nt][i] + bb);
      }
    }
  }
}

// ---------------------------------------------------------------------------
// Embed GEMM (R0-proven single-buffer structure):
// tslice[f32] & tbf[bf16] = gather(Ebf, tokens) @ Lbf^T + lin_b
// ---------------------------------------------------------------------------
__global__ __launch_bounds__(256) void gemm_emb_k(
    const u16* __restrict__ Ebf, const int* __restrict__ tokd,
    const u16* __restrict__ Lbf, const float* __restrict__ bias,
    float* __restrict__ outf, u16* __restrict__ outb)
{
  __shared__ u16 As[128 * 64];
  __shared__ u16 Bs[128 * 64];
  const int t = threadIdx.x;
  const int w = t >> 6;
  const int L = t & 63;
  const int q = L >> 4;
  const int lrow8 = L >> 3;
  const int sub = L & 7;
  const int swz = sub ^ lrow8;
  const int row0 = blockIdx.x * 128;

  f32x4 acc[4][4];
#pragma unroll
  for (int a = 0; a < 4; ++a)
#pragma unroll
    for (int b = 0; b < 4; ++b)
      acc[a][b] = f32x4{0.f, 0.f, 0.f, 0.f};

  const int mrow = (w & 1) * 64;
  const int ncol = (w >> 1) * 64;

  int4 cidx[4];
#pragma unroll
  for (int jj = 0; jj < 4; ++jj) {
    const int rit = w * 32 + jj * 8 + lrow8;
    cidx[jj].x = tokd[(row0 + rit) * LTOK + 0];
    cidx[jj].y = tokd[(row0 + rit) * LTOK + 1];
    cidx[jj].z = tokd[(row0 + rit) * LTOK + 2];
    cidx[jj].w = 0;
  }

#pragma unroll
  for (int k0 = 0; k0 < KD_EMB; k0 += 64) {
    __syncthreads();
#pragma unroll
    for (int jj = 0; jj < 4; ++jj) {
      const int id = ((const int*)&cidx[jj])[k0 >> 7];
      const u16* base = Ebf + (size_t)id * HD;
      const int rit = w * 32 + jj * 8 + lrow8;
      async16(base + (k0 & 127) + swz * 8, &As[(w * 32 + jj * 8) * 64]);
      async16(Lbf + (size_t)rit * KD_EMB + k0 + swz * 8, &Bs[(w * 32 + jj * 8) * 64]);
    }
    __syncthreads();
#pragma unroll
    for (int ks = 0; ks < 2; ++ks) {
      bf16x8 af[4], bfr[4];
      const int pc = ((ks * 4 + q) ^ (L & 7)) * 8;
#pragma unroll
      for (int mt = 0; mt < 4; ++mt)
        af[mt] = *(const bf16x8*)&As[(mrow + mt * 16 + (L & 15)) * 64 + pc];
#pragma unroll
      for (int nt = 0; nt < 4; ++nt)
        bfr[nt] = *(const bf16x8*)&Bs[(ncol + nt * 16 + (L & 15)) * 64 + pc];
#pragma unroll
      for (int mt = 0; mt < 4; ++mt)
#pragma unroll
        for (int nt = 0; nt < 4; ++nt)
          acc[mt][nt] = __builtin_amdgcn_mfma_f32_16x16x32_bf16(af[mt], bfr[nt], acc[mt][nt], 0, 0, 0);
    }
  }

#pragma unroll
  for (int nt = 0; nt < 4; ++nt) {
    const int col = ncol + nt * 16 + (L & 15);
    const float bb = bias[col];
#pragma unroll
    for (int mt = 0; mt < 4; ++mt) {
#pragma unroll
      for (int i = 0; i < 4; ++i) {
        const int row = row0 + mrow + mt * 16 + q * 4 + i;
        const float v = acc[mt][nt][i] + bb;
        outf[(size_t)row * NC_EMB + col] = v;
        outb[(size_t)row * NC_EMB + col] = f2bf(v);
      }
    }
  }
}

// ---------------------------------------------------------------------------
// LSTM cell: f = sum_k sig(pre_fk)*c_k ; gates ; c (f32), h (bf16),
// t += h (f32) and bf16 shadow tbf.
// ---------------------------------------------------------------------------
__global__ __launch_bounds__(256) void cell_k(
    const u16* __restrict__ pre, const int* __restrict__ idxs,
    const float* __restrict__ c_prev, float* __restrict__ c_cur,
    u16* __restrict__ h_cur, float* __restrict__ t_io, u16* __restrict__ tbf)
{
  const int g = blockIdx.x * 256 + threadIdx.x;
  const int r = g >> 7;
  const int j = g & 127;
  const u16* pr = pre + (size_t)r * NC_STEP;
  float f = 0.f;
#pragma unroll
  for (int k = 0; k < KCH; ++k) {
    const int id = idxs[r * KCH + k];
    const float cg = (id >= 1) ? c_prev[(size_t)(id - 1) * HD + j] : 0.f;
    f += sigm(bf2f(pr[k * HD + j])) * cg;
  }
  const float iv = sigm(bf2f(pr[4 * HD + j]));
  const float uv = tanh_fast(bf2f(pr[5 * HD + j]));
  const float ov = sigm(bf2f(pr[6 * HD + j]));
  const float cn = iv * uv + f;
  const float hv = ov * tanh_fast(cn);
  c_cur[g] = cn;
  h_cur[g] = f2bf(hv);
  const float tn = t_io[g] + hv;
  t_io[g] = tn;
  tbf[g] = f2bf(tn);
}

__global__ __launch_bounds__(256) void conv_k(const float* __restrict__ src,
                                              u16* __restrict__ dst, int n4)
{
  const int g = blockIdx.x * 256 + threadIdx.x;
  if (g < n4) {
    float4 v = ((const float4*)src)[g];
    ((ushort4*)dst)[g] = make_ushort4(f2bf(v.x), f2bf(v.y), f2bf(v.z), f2bf(v.w));
  }
}

// Build U_big[l][896][640] (bf16) = [Uf;Uiuo | W_w(mapped)] + fused f32 biases.
__global__ __launch_bounds__(256) void prep_k(
    const float* __restrict__ Uf_w, const float* __restrict__ Uf_b,
    const float* __restrict__ Uiuo_w, const float* __restrict__ Uiuo_b,
    const float* __restrict__ W_w, const float* __restrict__ W_b,
    u16* __restrict__ Ubig, float* __restrict__ biasbig)
{
  const int l = blockIdx.y;
  const int e = blockIdx.x * 256 + threadIdx.x;
  const int c = e / KD_STEP;
  const int k = e % KD_STEP;
  float v;
  if (k < 512) {
    v = (c < 512) ? Uf_w[((size_t)l * 512 + c) * 512 + k]
                  : Uiuo_w[((size_t)l * 384 + (c - 512)) * 512 + k];
  } else {
    const int q = k - 512;
    const int wr = (c < 512) ? (c & 127) : (128 + (c - 512));
    v = W_w[((size_t)l * 512 + wr) * 128 + q];
  }
  Ubig[((size_t)l * 896 + c) * 640 + k] = f2bf(v);
  if (e < 896) {
    const float b = (e < 512)
        ? (Uf_b[l * 512 + e] + W_b[l * 512 + (e & 127)])
        : (Uiuo_b[l * 384 + (e - 512)] + W_b[l * 512 + 128 + (e - 512)]);
    biasbig[l * 896 + e] = b;
  }
}

// Output (FLOAT32): hx = tile(t_final,2), cx = tile(c_final,2).
__global__ __launch_bounds__(256) void fin_k(
    const float* __restrict__ t_fin, const float* __restrict__ c_fin,
    float* __restrict__ out)
{
  const size_t NH = (size_t)NNODE * HD;
  const size_t g = (size_t)blockIdx.x * 256 + threadIdx.x;
  const float h = t_fin[g];
  const float c = c_fin[g];
  out[g] = h;
  out[NH + g] = h;
  out[2 * NH + g] = c;
  out[3 * NH + g] = c;
}

extern "C" void kernel_launch(void* const* d_in, const int* in_sizes, int n_in,
                              void* d_out, int out_size, void* d_ws, size_t ws_size,
                              hipStream_t stream)
{
  (void)in_sizes; (void)n_in; (void)out_size; (void)ws_size;
  const int*   tokens  = (const int*)d_in[0];
  const int*   indices = (const int*)d_in[1];
  const float* E       = (const float*)d_in[2];
  const float* lin_w   = (const float*)d_in[3];
  const float* lin_b   = (const float*)d_in[4];
  const float* Uf_w    = (const float*)d_in[5];
  const float* Uf_b    = (const float*)d_in[6];
  const float* Uiuo_w  = (const float*)d_in[7];
  const float* Uiuo_b  = (const float*)d_in[8];
  const float* W_w     = (const float*)d_in[9];
  const float* W_b     = (const float*)d_in[10];
  float* out = (float*)d_out;   // FLOAT32 output (R8-proven)

  const size_t NH = (size_t)NNODE * HD;

  char* ws = (char*)d_ws;
  size_t off = 0;
  auto alloc = [&](size_t bytes) -> void* {
    void* p = ws + off;
    off = (off + bytes + 255) & ~(size_t)255;
    return p;
  };
  u16*   Ubig    = (u16*)alloc((size_t)2 * 896 * 640 * 2);
  float* biasbig = (float*)alloc(2 * 896 * 4);
  u16*   Ebf     = (u16*)alloc((size_t)50000 * HD * 2);
  u16*   Lbf     = (u16*)alloc((size_t)HD * KD_EMB * 2);
  float* tslice  = (float*)alloc(NH * 4);
  u16*   tbf     = (u16*)alloc(NH * 2);
  u16*   h0a     = (u16*)alloc(NH * 2);
  u16*   h0b     = (u16*)alloc(NH * 2);
  u16*   h1a     = (u16*)alloc(NH * 2);
  u16*   h1b     = (u16*)alloc(NH * 2);
  float* c0a     = (float*)alloc(NH * 4);
  float* c0b     = (float*)alloc(NH * 4);
  float* c1a     = (float*)alloc(NH * 4);
  float* c1b     = (float*)alloc(NH * 4);
  u16*   pre     = (u16*)alloc((size_t)NNODE * NC_STEP * 2);
  u16*   zbuf    = (u16*)alloc(512);

  u16*   h0[2] = {h0a, h0b};
  u16*   h1[2] = {h1a, h1b};
  float* c0[2] = {c0a, c0b};
  float* c1[2] = {c1a, c1b};

  hipMemsetAsync(zbuf, 0, 512, stream);
  hipMemsetAsync(h0[0], 0, NH * 2, stream);
  hipMemsetAsync(h1[0], 0, NH * 2, stream);
  hipMemsetAsync(c0[0], 0, NH * 4, stream);
  hipMemsetAsync(c1[0], 0, NH * 4, stream);
  prep_k<<<dim3(2240, 2), 256, 0, stream>>>(Uf_w, Uf_b, Uiuo_w, Uiuo_b, W_w, W_b,
                                            Ubig, biasbig);
  conv_k<<<dim3((50000 * HD / 4 + 255) / 256), 256, 0, stream>>>(E, Ebf, 50000 * HD / 4);
  conv_k<<<dim3((HD * KD_EMB / 4 + 255) / 256), 256, 0, stream>>>(lin_w, Lbf, HD * KD_EMB / 4);

  for (int d = 0; d < DD; ++d) {
    const int ri = d & 1, wi = (d + 1) & 1;
    const int* idxd = indices + (size_t)d * NNODE * KCH;
    const int* tokd = tokens + (size_t)d * NNODE * LTOK;

    // tslice (f32) + tbf (bf16) = gather(Ebf, tokens[d]) @ Lbf^T + lin_b
    gemm_emb_k<<<dim3(NNODE / 128), 256, 0, stream>>>(
        Ebf, tokd, Lbf, lin_b, tslice, tbf);

    for (int l = 0; l < 2; ++l) {
      const u16*   hp = (l == 0) ? h0[ri] : h1[ri];
      u16*         hc = (l == 0) ? h0[wi] : h1[wi];
      const float* cp = (l == 0) ? c0[ri] : c1[ri];
      float*       cc = (l == 0) ? c0[wi] : c1[wi];
      const u16* Ul = Ubig + (size_t)l * 896 * 640;
      const float* bl = biasbig + l * 896;
      gemm8_k<<<dim3((NNODE / BM) * (NC_STEP / BN)), 512, 0, stream>>>(
          hp, tbf, idxd, Ul, bl, pre, zbuf);
      cell_k<<<dim3((int)(NH / 256)), 256, 0, stream>>>(
          pre, idxd, cp, cc, hc, tslice, tbf);
    }
  }
  // after d=11: tslice = t_final, c1[0] = c_final
  fin_k<<<dim3((int)(NH / 256)), 256, 0, stream>>>(tslice, c1[0], out);
}